// Round 8
// baseline (510.831 us; speedup 1.0000x reference)
//
#include <hip/hip_runtime.h>

#define Bb 32
#define Ll 1024
#define LMD 1024
#define Dd 128
#define Rr 3
#define NLAYER 2
#define Cc 8
#define Nn (Bb*Ll)          // 32768
#define Ee 524288
#define NSEG (Nn*Rr)        // 98304
#define LN_EPS 1e-5f
#define ASTRIDE 392         // shorts per LDS A-row: 384 + 8 pad (784 B = 49x16)

typedef __attribute__((ext_vector_type(8))) short bf16x8;
typedef __attribute__((ext_vector_type(4))) float f32x4;

__device__ inline short f2bf(float f) {
    unsigned u = __builtin_bit_cast(unsigned, f);
    u += 0x7fff + ((u >> 16) & 1);           // RNE
    return (short)(u >> 16);
}
__device__ inline float bf2f(unsigned short s) {
    unsigned u = ((unsigned)s) << 16;
    return __builtin_bit_cast(float, u);
}

// ---- prep: weight pack (blocks 0..1023) + edge histogram (blocks 1024..3071)
__global__ __launch_bounds__(256) void prep_kernel(
    const float* __restrict__ lmW, const float* __restrict__ Wrel,
    const float* __restrict__ Wroot, short* __restrict__ Wp_all,
    const int* __restrict__ dst, const int* __restrict__ et,
    int* __restrict__ counts)
{
    int bid = blockIdx.x;
    if (bid < 1024) {
        int idx = bid * 256 + threadIdx.x;   // 0..262143
        float v;
        if (idx < 131072) {
            int kk = idx & 31, n = (idx >> 5) & 127, ks = idx >> 12;
            v = lmW[n * 1024 + ks * 32 + kk];
        } else {
            int j = idx - 131072;
            int layer = j >> 16;
            int kk = j & 31, n = (j >> 5) & 127, ks = (j >> 12) & 15;
            int k = ks * 32 + kk;
            v = (k < 384) ? Wrel[(size_t)layer * 49152 + (size_t)k * 128 + n]
                          : Wroot[(size_t)layer * 16384 + (size_t)(k - 384) * 128 + n];
        }
        Wp_all[idx] = f2bf(v);
    } else {
        int e = (bid - 1024) * 256 + threadIdx.x;   // 0..Ee-1
        atomicAdd(&counts[dst[e] * 3 + et[e]], 1);
    }
}

// ---- LM head GEMM (MFMA bf16) + bias + ReLU + fused LayerNorm (known-good) ----
__global__ __launch_bounds__(256) void lm_gemm_ln_kernel(
    const float* __restrict__ A,        // [M,1024] fp32
    const short* __restrict__ Wp,       // [32][128][32] bf16 frag-packed
    const float* __restrict__ bias,     // [128]
    const float* __restrict__ lng, const float* __restrict__ lnb,
    short* __restrict__ lm_bf16)
{
    const int wv   = threadIdx.x >> 6;
    const int lane = threadIdx.x & 63;
    const int m16  = lane & 15;
    const int quad = lane >> 4;
    const int row_frag = blockIdx.x * 64 + wv * 16 + m16;
    const float* arow = A + (size_t)row_frag * 1024 + quad * 8;

    f32x4 acc[8];
    #pragma unroll
    for (int i = 0; i < 8; ++i) acc[i] = (f32x4){0.f, 0.f, 0.f, 0.f};

    #pragma unroll 2
    for (int ks = 0; ks < 32; ++ks) {
        const short* wpb = Wp + ks * 4096 + m16 * 32 + quad * 8;
        bf16x8 bfr[8];
        #pragma unroll
        for (int nt = 0; nt < 8; ++nt)
            bfr[nt] = *(const bf16x8*)(wpb + nt * 512);
        const float4* ap = (const float4*)(arow + ks * 32);
        float4 a0 = ap[0], a1 = ap[1];
        union { bf16x8 v; short s[8]; } af;
        af.s[0] = f2bf(a0.x); af.s[1] = f2bf(a0.y);
        af.s[2] = f2bf(a0.z); af.s[3] = f2bf(a0.w);
        af.s[4] = f2bf(a1.x); af.s[5] = f2bf(a1.y);
        af.s[6] = f2bf(a1.z); af.s[7] = f2bf(a1.w);
        #pragma unroll
        for (int nt = 0; nt < 8; ++nt)
            acc[nt] = __builtin_amdgcn_mfma_f32_16x16x32_bf16(af.v, bfr[nt], acc[nt], 0, 0, 0);
    }

    float v[8][4];
    #pragma unroll
    for (int nt = 0; nt < 8; ++nt) {
        float bs = bias[nt * 16 + m16];
        #pragma unroll
        for (int r = 0; r < 4; ++r) v[nt][r] = fmaxf(acc[nt][r] + bs, 0.f);
    }
    float gv[8], bv[8];
    #pragma unroll
    for (int nt = 0; nt < 8; ++nt) { gv[nt] = lng[nt * 16 + m16]; bv[nt] = lnb[nt * 16 + m16]; }

    const int row0 = blockIdx.x * 64 + wv * 16 + quad * 4;
    #pragma unroll
    for (int r = 0; r < 4; ++r) {
        float s = 0.f;
        #pragma unroll
        for (int nt = 0; nt < 8; ++nt) s += v[nt][r];
        s += __shfl_xor(s, 1, 64); s += __shfl_xor(s, 2, 64);
        s += __shfl_xor(s, 4, 64); s += __shfl_xor(s, 8, 64);
        float mu = s * (1.f / 128.f);
        float q = 0.f;
        #pragma unroll
        for (int nt = 0; nt < 8; ++nt) { float d = v[nt][r] - mu; q += d * d; }
        q += __shfl_xor(q, 1, 64); q += __shfl_xor(q, 2, 64);
        q += __shfl_xor(q, 4, 64); q += __shfl_xor(q, 8, 64);
        float rs = rsqrtf(q * (1.f / 128.f) + LN_EPS);
        size_t rowoff = (size_t)(row0 + r) * 128;
        #pragma unroll
        for (int nt = 0; nt < 8; ++nt) {
            float o = (v[nt][r] - mu) * rs * gv[nt] + bv[nt];
            lm_bf16[rowoff + nt * 16 + m16] = f2bf(o);
        }
    }
}

// ---- FUSED aggregate + conv GEMM (block-local, one barrier) ----
// Block b owns rows [64b,64b+64). Phase 1: aggregate the block's own 192
// (node,rel) segments into LDS (bf16, padded rows). Phase 2: verbatim conv
// MFMA with A[ks<12] from LDS, A[ks>=12] (root term) from global x.
__global__ __launch_bounds__(256) void agg_conv_kernel(
    const short* __restrict__ x,        // [N,128] bf16 (node features)
    const int* __restrict__ row_ptr, const int* __restrict__ edge_src,
    const short* __restrict__ Wp,       // [16][128][32] bf16 frag-packed
    const float* __restrict__ bias,
    short* __restrict__ out_bf16)       // [N,128]
{
    __shared__ short As[64 * ASTRIDE];  // 50176 B
    const int wv   = threadIdx.x >> 6;
    const int lane = threadIdx.x & 63;
    const int row0 = blockIdx.x * 64;

    // phase 1: segments si = i*3+r, i=local row, r=relation; wave-interleaved
    for (int si = wv; si < 192; si += 4) {
        int i = si / 3, r = si - i * 3;
        int seg = (row0 + i) * 3 + r;
        int b = row_ptr[seg], e = row_ptr[seg + 1];
        float ax = 0.f, ay = 0.f;
        int j = b;
        for (; j + 4 <= e; j += 4) {
            int s0 = edge_src[j],     s1 = edge_src[j + 1];
            int s2 = edge_src[j + 2], s3 = edge_src[j + 3];
            unsigned u0 = *(const unsigned*)(x + (size_t)s0 * 128 + lane * 2);
            unsigned u1 = *(const unsigned*)(x + (size_t)s1 * 128 + lane * 2);
            unsigned u2 = *(const unsigned*)(x + (size_t)s2 * 128 + lane * 2);
            unsigned u3 = *(const unsigned*)(x + (size_t)s3 * 128 + lane * 2);
            ax += bf2f((unsigned short)(u0 & 0xffff)) + bf2f((unsigned short)(u1 & 0xffff))
                + bf2f((unsigned short)(u2 & 0xffff)) + bf2f((unsigned short)(u3 & 0xffff));
            ay += bf2f((unsigned short)(u0 >> 16)) + bf2f((unsigned short)(u1 >> 16))
                + bf2f((unsigned short)(u2 >> 16)) + bf2f((unsigned short)(u3 >> 16));
        }
        for (; j + 2 <= e; j += 2) {
            int s0 = edge_src[j], s1 = edge_src[j + 1];
            unsigned u0 = *(const unsigned*)(x + (size_t)s0 * 128 + lane * 2);
            unsigned u1 = *(const unsigned*)(x + (size_t)s1 * 128 + lane * 2);
            ax += bf2f((unsigned short)(u0 & 0xffff)) + bf2f((unsigned short)(u1 & 0xffff));
            ay += bf2f((unsigned short)(u0 >> 16))    + bf2f((unsigned short)(u1 >> 16));
        }
        if (j < e) {
            int s0 = edge_src[j];
            unsigned u0 = *(const unsigned*)(x + (size_t)s0 * 128 + lane * 2);
            ax += bf2f((unsigned short)(u0 & 0xffff));
            ay += bf2f((unsigned short)(u0 >> 16));
        }
        int cnt = e - b;
        float inv = 1.f / (float)(cnt > 0 ? cnt : 1);
        unsigned short lo = (unsigned short)f2bf(ax * inv);
        unsigned short hi = (unsigned short)f2bf(ay * inv);
        *(unsigned*)(&As[i * ASTRIDE + r * 128 + lane * 2]) =
            (unsigned)lo | ((unsigned)hi << 16);
    }
    __syncthreads();

    // phase 2: conv MFMA (verbatim structure)
    const int m16  = lane & 15;
    const int quad = lane >> 4;
    const int li   = wv * 16 + m16;                 // local row for A-fragment
    const short* a2row = x + (size_t)(row0 + li) * 128 + quad * 8;

    f32x4 acc[8];
    #pragma unroll
    for (int i = 0; i < 8; ++i) acc[i] = (f32x4){0.f, 0.f, 0.f, 0.f};

    #pragma unroll 2
    for (int ks = 0; ks < 16; ++ks) {
        const short* wpb = Wp + ks * 4096 + m16 * 32 + quad * 8;
        bf16x8 bfr[8];
        #pragma unroll
        for (int nt = 0; nt < 8; ++nt)
            bfr[nt] = *(const bf16x8*)(wpb + nt * 512);
        const short* ar = (ks < 12) ? (&As[li * ASTRIDE + ks * 32 + quad * 8])
                                    : (a2row + (ks - 12) * 32);
        bf16x8 af = *(const bf16x8*)ar;
        #pragma unroll
        for (int nt = 0; nt < 8; ++nt)
            acc[nt] = __builtin_amdgcn_mfma_f32_16x16x32_bf16(af, bfr[nt], acc[nt], 0, 0, 0);
    }

    const int orow0 = row0 + wv * 16 + quad * 4;
    #pragma unroll
    for (int nt = 0; nt < 8; ++nt) {
        float bs = bias[nt * 16 + m16];
        #pragma unroll
        for (int r = 0; r < 4; ++r) {
            float o = fmaxf(acc[nt][r] + bs, 0.f);
            out_bf16[(size_t)(orow0 + r) * 128 + nt * 16 + m16] = f2bf(o);
        }
    }
}

// ---- CSR scan (hierarchical, r6-verified) ----
__global__ __launch_bounds__(256) void scan_blk_kernel(
    const int* __restrict__ counts, int* __restrict__ excl, int* __restrict__ blksum)
{
    __shared__ int wsum[4];
    int t = threadIdx.x, lane = t & 63, wv = t >> 6;
    int g = blockIdx.x * 256 + t;
    int v = counts[g];
    int x = v;
    #pragma unroll
    for (int off = 1; off < 64; off <<= 1) {
        int y = __shfl_up(x, off, 64);
        if (lane >= off) x += y;
    }
    if (lane == 63) wsum[wv] = x;
    __syncthreads();
    int woff = 0;
    for (int i = 0; i < wv; ++i) woff += wsum[i];
    excl[g] = woff + x - v;
    if (t == 255) blksum[blockIdx.x] = woff + x;
}

__global__ __launch_bounds__(256) void scan_add_kernel(
    const int* __restrict__ excl, const int* __restrict__ blksum,
    int* __restrict__ row_ptr)
{
    __shared__ int ws4[4];
    __shared__ int off_sh;
    const int t = threadIdx.x, bid = blockIdx.x;
    int s = 0;
    for (int j = t; j < bid; j += 256) s += blksum[j];
    #pragma unroll
    for (int o = 32; o > 0; o >>= 1) s += __shfl_xor(s, o, 64);
    if ((t & 63) == 0) ws4[t >> 6] = s;
    __syncthreads();
    if (t == 0) off_sh = ws4[0] + ws4[1] + ws4[2] + ws4[3];
    __syncthreads();
    int g = bid * 256 + t;
    row_ptr[g] = excl[g] + off_sh;
    if (g == 0) row_ptr[NSEG] = Ee;
}

__global__ __launch_bounds__(256) void scatter_kernel(
    const int* __restrict__ src, const int* __restrict__ dst, const int* __restrict__ et,
    const int* __restrict__ row_ptr, int* __restrict__ fill, int* __restrict__ edge_src)
{
    int e = blockIdx.x * 256 + threadIdx.x;
    int s = dst[e] * 3 + et[e];
    int pos = row_ptr[s] + atomicAdd(&fill[s], 1);
    edge_src[pos] = src[e];
}

// ---- classifier + masked CE loss (lm bf16, g bf16) + fused finalize ----
__global__ __launch_bounds__(256) void cls_loss_kernel(
    const short* __restrict__ lm, const short* __restrict__ g,
    const float* __restrict__ clsW, const float* __restrict__ clsb,
    const int* __restrict__ mask, const int* __restrict__ labels,
    float* __restrict__ logits, float* __restrict__ accb,
    unsigned* __restrict__ ticket, float* __restrict__ loss_out)
{
    __shared__ float W[2048];
    for (int i = threadIdx.x; i < 2048; i += 256) W[i] = clsW[i];
    __syncthreads();
    int n = blockIdx.x * 256 + threadIdx.x;
    float l[8];
    #pragma unroll
    for (int c = 0; c < 8; ++c) l[c] = clsb[c];
    const short* lmr = lm + (size_t)n * 128;
    const short* gr  = g  + (size_t)n * 128;
    #pragma unroll 2
    for (int h = 0; h < 128; h += 8) {
        uint4 raw = *(const uint4*)(lmr + h);
        float a[8];
        a[0] = bf2f((unsigned short)(raw.x & 0xffff)); a[1] = bf2f((unsigned short)(raw.x >> 16));
        a[2] = bf2f((unsigned short)(raw.y & 0xffff)); a[3] = bf2f((unsigned short)(raw.y >> 16));
        a[4] = bf2f((unsigned short)(raw.z & 0xffff)); a[5] = bf2f((unsigned short)(raw.z >> 16));
        a[6] = bf2f((unsigned short)(raw.w & 0xffff)); a[7] = bf2f((unsigned short)(raw.w >> 16));
        #pragma unroll
        for (int c = 0; c < 8; ++c) {
            const float* w = &W[c * 256 + h];
            #pragma unroll
            for (int j = 0; j < 8; ++j) l[c] = fmaf(a[j], w[j], l[c]);
        }
    }
    #pragma unroll 2
    for (int h = 0; h < 128; h += 8) {
        uint4 raw = *(const uint4*)(gr + h);
        float a[8];
        a[0] = bf2f((unsigned short)(raw.x & 0xffff)); a[1] = bf2f((unsigned short)(raw.x >> 16));
        a[2] = bf2f((unsigned short)(raw.y & 0xffff)); a[3] = bf2f((unsigned short)(raw.y >> 16));
        a[4] = bf2f((unsigned short)(raw.z & 0xffff)); a[5] = bf2f((unsigned short)(raw.z >> 16));
        a[6] = bf2f((unsigned short)(raw.w & 0xffff)); a[7] = bf2f((unsigned short)(raw.w >> 16));
        #pragma unroll
        for (int c = 0; c < 8; ++c) {
            const float* w = &W[c * 256 + 128 + h];
            #pragma unroll
            for (int j = 0; j < 8; ++j) l[c] = fmaf(a[j], w[j], l[c]);
        }
    }
    #pragma unroll
    for (int c = 0; c < 8; ++c) logits[(size_t)n * 8 + c] = l[c];

    float m = l[0];
    #pragma unroll
    for (int c = 1; c < 8; ++c) m = fmaxf(m, l[c]);
    float ss = 0.f;
    #pragma unroll
    for (int c = 0; c < 8; ++c) ss += expf(l[c] - m);
    float lse = m + logf(ss);
    int y = labels[n];
    float ly = l[0];
    #pragma unroll
    for (int c = 1; c < 8; ++c) ly = (y == c) ? l[c] : ly;
    float nll = lse - ly;
    bool valid = (mask[n] == 1);
    float lv = valid ? nll : 0.f;
    float cv = valid ? 1.f : 0.f;
    #pragma unroll
    for (int off = 32; off > 0; off >>= 1) {
        lv += __shfl_down(lv, off, 64);
        cv += __shfl_down(cv, off, 64);
    }
    if ((threadIdx.x & 63) == 0) { atomicAdd(&accb[0], lv); atomicAdd(&accb[1], cv); }

    __threadfence();
    if (threadIdx.x == 0) {
        unsigned t = atomicAdd(ticket, 1u);
        if (t == gridDim.x - 1) {
            float lsum = atomicAdd(&accb[0], 0.f);
            float csum = atomicAdd(&accb[1], 0.f);
            loss_out[0] = lsum / fmaxf(csum, 1.f);
        }
    }
}

// ---- launcher ----
extern "C" void kernel_launch(void* const* d_in, const int* in_sizes, int n_in,
                              void* d_out, int out_size, void* d_ws, size_t ws_size,
                              hipStream_t stream)
{
    const float* output = (const float*)d_in[0];
    const int* edge_index = (const int*)d_in[1];
    const int* edge_type  = (const int*)d_in[2];
    const int* attn       = (const int*)d_in[3];
    const int* labels     = (const int*)d_in[4];
    const float* lmW   = (const float*)d_in[5];
    const float* lmb   = (const float*)d_in[6];
    const float* lng   = (const float*)d_in[7];
    const float* lnb   = (const float*)d_in[8];
    const float* Wrel  = (const float*)d_in[9];
    const float* Wroot = (const float*)d_in[10];
    const float* convb = (const float*)d_in[11];
    const float* clsW  = (const float*)d_in[12];
    const float* clsb  = (const float*)d_in[13];

    char* ws = (char*)d_ws;
    short* lm_bf  = (short*)ws;                          ws += (size_t)Nn * Dd * 2;
    short* x1_bf  = (short*)ws;                          ws += (size_t)Nn * Dd * 2;
    short* x2_bf  = (short*)ws;                          ws += (size_t)Nn * Dd * 2;
    short* Wp_all = (short*)ws;                          ws += (size_t)262144 * 2;
    // zeroed region: [accb+ticket pad | counts | fill] contiguous
    float* accb   = (float*)ws;                          ws += 64;
    int* counts   = (int*)ws;                            ws += (size_t)NSEG * 4;
    int* fill     = (int*)ws;                            ws += (size_t)NSEG * 4;
    int* row_ptr  = (int*)ws;                            ws += (size_t)(NSEG + 4) * 4;
    int* excl     = (int*)ws;                            ws += (size_t)NSEG * 4;
    int* blksum   = (int*)ws;                            ws += 512 * 4;
    int* edge_src = (int*)ws;

    unsigned* ticket = (unsigned*)(accb + 2);            // inside zeroed pad

    short* Wp_lm = Wp_all;
    short* Wp_c0 = Wp_all + 131072;
    short* Wp_c1 = Wp_all + 131072 + 65536;

    const int* e_src = edge_index;
    const int* e_dst = edge_index + Ee;

    hipMemsetAsync(accb, 0, 64 + 2 * (size_t)NSEG * 4, stream);

    // pack weights + edge histogram (fused)
    prep_kernel<<<dim3(1024 + Ee / 256), dim3(256), 0, stream>>>(
        lmW, Wrel, Wroot, Wp_all, e_dst, edge_type, counts);

    // LM head + ReLU + fused LN
    lm_gemm_ln_kernel<<<dim3(Nn / 64), dim3(256), 0, stream>>>(
        output, Wp_lm, lmb, lng, lnb, lm_bf);

    // CSR over (dst, relation)
    scan_blk_kernel<<<dim3(NSEG / 256), dim3(256), 0, stream>>>(counts, excl, blksum);
    scan_add_kernel<<<dim3(NSEG / 256), dim3(256), 0, stream>>>(excl, blksum, row_ptr);
    scatter_kernel<<<dim3(Ee / 256), dim3(256), 0, stream>>>(
        e_src, e_dst, edge_type, row_ptr, fill, edge_src);

    // RGCN layers: fused aggregate+conv (block-local)
    agg_conv_kernel<<<dim3(Nn / 64), dim3(256), 0, stream>>>(
        lm_bf, row_ptr, edge_src, Wp_c0, convb, x1_bf);
    agg_conv_kernel<<<dim3(Nn / 64), dim3(256), 0, stream>>>(
        x1_bf, row_ptr, edge_src, Wp_c1, convb + Dd, x2_bf);

    // classifier + loss + fused finalize
    float* logits = (float*)d_out + 1;
    cls_loss_kernel<<<dim3(Nn / 256), dim3(256), 0, stream>>>(
        lm_bf, x2_bf, clsW, clsb, attn, labels, logits, accb, ticket, (float*)d_out);
}

// Round 10
// 452.840 us; speedup vs baseline: 1.1281x; 1.1281x over previous
//
#include <hip/hip_runtime.h>

#define Bb 32
#define Ll 1024
#define LMD 1024
#define Dd 128
#define Rr 3
#define NLAYER 2
#define Cc 8
#define Nn (Bb*Ll)          // 32768
#define Ee 524288
#define NSEG (Nn*Rr)        // 98304
#define LN_EPS 1e-5f
#define FIXSCALE 1073741824.0f      // 2^30
#define FIXINV   (1.0f / 1073741824.0f)

typedef __attribute__((ext_vector_type(8))) short bf16x8;
typedef __attribute__((ext_vector_type(4))) float f32x4;

__device__ inline short f2bf(float f) {
    unsigned u = __builtin_bit_cast(unsigned, f);
    u += 0x7fff + ((u >> 16) & 1);           // RNE
    return (short)(u >> 16);
}
__device__ inline float bf2f(unsigned short s) {
    unsigned u = ((unsigned)s) << 16;
    return __builtin_bit_cast(float, u);
}
// deterministic fixed-point quantizer (order-independent accumulation)
__device__ inline long long q30(float v) {
    return (long long)llrintf(v * FIXSCALE);
}

// ---- prep: weight pack (blocks 0..1023) + edge histogram (blocks 1024..3071)
__global__ __launch_bounds__(256) void prep_kernel(
    const float* __restrict__ lmW, const float* __restrict__ Wrel,
    const float* __restrict__ Wroot, short* __restrict__ Wp_all,
    const int* __restrict__ dst, const int* __restrict__ et,
    int* __restrict__ counts)
{
    int bid = blockIdx.x;
    if (bid < 1024) {
        int idx = bid * 256 + threadIdx.x;   // 0..262143
        float v;
        if (idx < 131072) {
            int kk = idx & 31, n = (idx >> 5) & 127, ks = idx >> 12;
            v = lmW[n * 1024 + ks * 32 + kk];
        } else {
            int j = idx - 131072;
            int layer = j >> 16;
            int kk = j & 31, n = (j >> 5) & 127, ks = (j >> 12) & 15;
            int k = ks * 32 + kk;
            v = (k < 384) ? Wrel[(size_t)layer * 49152 + (size_t)k * 128 + n]
                          : Wroot[(size_t)layer * 16384 + (size_t)(k - 384) * 128 + n];
        }
        Wp_all[idx] = f2bf(v);
    } else {
        int e = (bid - 1024) * 256 + threadIdx.x;   // 0..Ee-1
        atomicAdd(&counts[dst[e] * 3 + et[e]], 1);
    }
}

// ---- LM head GEMM (MFMA bf16) + bias + ReLU + fused LayerNorm (r7 verbatim) ----
__global__ __launch_bounds__(256) void lm_gemm_ln_kernel(
    const float* __restrict__ A,        // [M,1024] fp32
    const short* __restrict__ Wp,       // [32][128][32] bf16 frag-packed
    const float* __restrict__ bias,     // [128]
    const float* __restrict__ lng, const float* __restrict__ lnb,
    short* __restrict__ lm_bf16)
{
    const int wv   = threadIdx.x >> 6;
    const int lane = threadIdx.x & 63;
    const int m16  = lane & 15;
    const int quad = lane >> 4;
    const int row_frag = blockIdx.x * 64 + wv * 16 + m16;
    const float* arow = A + (size_t)row_frag * 1024 + quad * 8;

    f32x4 acc[8];
    #pragma unroll
    for (int i = 0; i < 8; ++i) acc[i] = (f32x4){0.f, 0.f, 0.f, 0.f};

    #pragma unroll 2
    for (int ks = 0; ks < 32; ++ks) {
        const short* wpb = Wp + ks * 4096 + m16 * 32 + quad * 8;
        bf16x8 bfr[8];
        #pragma unroll
        for (int nt = 0; nt < 8; ++nt)
            bfr[nt] = *(const bf16x8*)(wpb + nt * 512);
        const float4* ap = (const float4*)(arow + ks * 32);
        float4 a0 = ap[0], a1 = ap[1];
        union { bf16x8 v; short s[8]; } af;
        af.s[0] = f2bf(a0.x); af.s[1] = f2bf(a0.y);
        af.s[2] = f2bf(a0.z); af.s[3] = f2bf(a0.w);
        af.s[4] = f2bf(a1.x); af.s[5] = f2bf(a1.y);
        af.s[6] = f2bf(a1.z); af.s[7] = f2bf(a1.w);
        #pragma unroll
        for (int nt = 0; nt < 8; ++nt)
            acc[nt] = __builtin_amdgcn_mfma_f32_16x16x32_bf16(af.v, bfr[nt], acc[nt], 0, 0, 0);
    }

    float v[8][4];
    #pragma unroll
    for (int nt = 0; nt < 8; ++nt) {
        float bs = bias[nt * 16 + m16];
        #pragma unroll
        for (int r = 0; r < 4; ++r) v[nt][r] = fmaxf(acc[nt][r] + bs, 0.f);
    }
    float gv[8], bv[8];
    #pragma unroll
    for (int nt = 0; nt < 8; ++nt) { gv[nt] = lng[nt * 16 + m16]; bv[nt] = lnb[nt * 16 + m16]; }

    const int row0 = blockIdx.x * 64 + wv * 16 + quad * 4;
    #pragma unroll
    for (int r = 0; r < 4; ++r) {
        float s = 0.f;
        #pragma unroll
        for (int nt = 0; nt < 8; ++nt) s += v[nt][r];
        s += __shfl_xor(s, 1, 64); s += __shfl_xor(s, 2, 64);
        s += __shfl_xor(s, 4, 64); s += __shfl_xor(s, 8, 64);
        float mu = s * (1.f / 128.f);
        float q = 0.f;
        #pragma unroll
        for (int nt = 0; nt < 8; ++nt) { float d = v[nt][r] - mu; q += d * d; }
        q += __shfl_xor(q, 1, 64); q += __shfl_xor(q, 2, 64);
        q += __shfl_xor(q, 4, 64); q += __shfl_xor(q, 8, 64);
        float rs = rsqrtf(q * (1.f / 128.f) + LN_EPS);
        size_t rowoff = (size_t)(row0 + r) * 128;
        #pragma unroll
        for (int nt = 0; nt < 8; ++nt) {
            float o = (v[nt][r] - mu) * rs * gv[nt] + bv[nt];
            lm_bf16[rowoff + nt * 16 + m16] = f2bf(o);
        }
    }
}

// ---- conv GEMM (MFMA bf16): out = relu([agg|x] * Wc + bias), K=512 (r7 verbatim) ----
__global__ __launch_bounds__(256) void conv_gemm_kernel(
    const short* __restrict__ A1,       // [N,384] bf16 (agg)
    const short* __restrict__ A2,       // [N,128] bf16 (x)
    const short* __restrict__ Wp,       // [16][128][32] bf16 frag-packed
    const float* __restrict__ bias,
    short* __restrict__ out_bf16)       // [N,128]
{
    const int wv   = threadIdx.x >> 6;
    const int lane = threadIdx.x & 63;
    const int m16  = lane & 15;
    const int quad = lane >> 4;
    const int row_frag = blockIdx.x * 64 + wv * 16 + m16;
    const short* a1row = A1 + (size_t)row_frag * 384 + quad * 8;
    const short* a2row = A2 + (size_t)row_frag * 128 + quad * 8;

    f32x4 acc[8];
    #pragma unroll
    for (int i = 0; i < 8; ++i) acc[i] = (f32x4){0.f, 0.f, 0.f, 0.f};

    #pragma unroll 2
    for (int ks = 0; ks < 16; ++ks) {
        const short* wpb = Wp + ks * 4096 + m16 * 32 + quad * 8;
        bf16x8 bfr[8];
        #pragma unroll
        for (int nt = 0; nt < 8; ++nt)
            bfr[nt] = *(const bf16x8*)(wpb + nt * 512);
        const short* ar = (ks < 12) ? (a1row + ks * 32) : (a2row + (ks - 12) * 32);
        bf16x8 af = *(const bf16x8*)ar;
        #pragma unroll
        for (int nt = 0; nt < 8; ++nt)
            acc[nt] = __builtin_amdgcn_mfma_f32_16x16x32_bf16(af, bfr[nt], acc[nt], 0, 0, 0);
    }

    const int row0 = blockIdx.x * 64 + wv * 16 + quad * 4;
    #pragma unroll
    for (int nt = 0; nt < 8; ++nt) {
        float bs = bias[nt * 16 + m16];
        #pragma unroll
        for (int r = 0; r < 4; ++r) {
            float o = fmaxf(acc[nt][r] + bs, 0.f);
            out_bf16[(size_t)(row0 + r) * 128 + nt * 16 + m16] = f2bf(o);
        }
    }
}

// ---- CSR scan (hierarchical, r6-verified) ----
__global__ __launch_bounds__(256) void scan_blk_kernel(
    const int* __restrict__ counts, int* __restrict__ excl, int* __restrict__ blksum)
{
    __shared__ int wsum[4];
    int t = threadIdx.x, lane = t & 63, wv = t >> 6;
    int g = blockIdx.x * 256 + t;
    int v = counts[g];
    int x = v;
    #pragma unroll
    for (int off = 1; off < 64; off <<= 1) {
        int y = __shfl_up(x, off, 64);
        if (lane >= off) x += y;
    }
    if (lane == 63) wsum[wv] = x;
    __syncthreads();
    int woff = 0;
    for (int i = 0; i < wv; ++i) woff += wsum[i];
    excl[g] = woff + x - v;
    if (t == 255) blksum[blockIdx.x] = woff + x;
}

__global__ __launch_bounds__(256) void scan_add_kernel(
    const int* __restrict__ excl, const int* __restrict__ blksum,
    int* __restrict__ row_ptr)
{
    __shared__ int ws4[4];
    __shared__ int off_sh;
    const int t = threadIdx.x, bid = blockIdx.x;
    int s = 0;
    for (int j = t; j < bid; j += 256) s += blksum[j];
    #pragma unroll
    for (int o = 32; o > 0; o >>= 1) s += __shfl_xor(s, o, 64);
    if ((t & 63) == 0) ws4[t >> 6] = s;
    __syncthreads();
    if (t == 0) off_sh = ws4[0] + ws4[1] + ws4[2] + ws4[3];
    __syncthreads();
    int g = bid * 256 + t;
    row_ptr[g] = excl[g] + off_sh;
    if (g == 0) row_ptr[NSEG] = Ee;
}

__global__ __launch_bounds__(256) void scatter_kernel(
    const int* __restrict__ src, const int* __restrict__ dst, const int* __restrict__ et,
    const int* __restrict__ row_ptr, int* __restrict__ fill, int* __restrict__ edge_src)
{
    int e = blockIdx.x * 256 + threadIdx.x;
    int s = dst[e] * 3 + et[e];
    int pos = row_ptr[s] + atomicAdd(&fill[s], 1);
    edge_src[pos] = src[e];
}

// ---- per-(node,relation) mean aggregation, DETERMINISTIC int64 fixed-point ----
// Edge order from scatter is nondeterministic; integer accumulation is exactly
// commutative, so the result is order-independent (the r5/r9 flake fix).
__global__ __launch_bounds__(256) void aggregate_kernel(
    const short* __restrict__ x, const int* __restrict__ row_ptr,
    const int* __restrict__ edge_src, short* __restrict__ agg)
{
    int seg  = blockIdx.x * 4 + (threadIdx.x >> 6);
    int lane = threadIdx.x & 63;
    int b = row_ptr[seg], e = row_ptr[seg + 1];
    int n = seg / 3, r = seg - n * 3;
    long long ax = 0, ay = 0;
    int i = b;
    for (; i + 4 <= e; i += 4) {
        int s0 = edge_src[i],     s1 = edge_src[i + 1];
        int s2 = edge_src[i + 2], s3 = edge_src[i + 3];
        unsigned u0 = *(const unsigned*)(x + (size_t)s0 * 128 + lane * 2);
        unsigned u1 = *(const unsigned*)(x + (size_t)s1 * 128 + lane * 2);
        unsigned u2 = *(const unsigned*)(x + (size_t)s2 * 128 + lane * 2);
        unsigned u3 = *(const unsigned*)(x + (size_t)s3 * 128 + lane * 2);
        ax += q30(bf2f((unsigned short)(u0 & 0xffff))) + q30(bf2f((unsigned short)(u1 & 0xffff)))
            + q30(bf2f((unsigned short)(u2 & 0xffff))) + q30(bf2f((unsigned short)(u3 & 0xffff)));
        ay += q30(bf2f((unsigned short)(u0 >> 16))) + q30(bf2f((unsigned short)(u1 >> 16)))
            + q30(bf2f((unsigned short)(u2 >> 16))) + q30(bf2f((unsigned short)(u3 >> 16)));
    }
    for (; i + 2 <= e; i += 2) {
        int s0 = edge_src[i], s1 = edge_src[i + 1];
        unsigned u0 = *(const unsigned*)(x + (size_t)s0 * 128 + lane * 2);
        unsigned u1 = *(const unsigned*)(x + (size_t)s1 * 128 + lane * 2);
        ax += q30(bf2f((unsigned short)(u0 & 0xffff))) + q30(bf2f((unsigned short)(u1 & 0xffff)));
        ay += q30(bf2f((unsigned short)(u0 >> 16)))    + q30(bf2f((unsigned short)(u1 >> 16)));
    }
    if (i < e) {
        int s0 = edge_src[i];
        unsigned u0 = *(const unsigned*)(x + (size_t)s0 * 128 + lane * 2);
        ax += q30(bf2f((unsigned short)(u0 & 0xffff)));
        ay += q30(bf2f((unsigned short)(u0 >> 16)));
    }
    int cnt = e - b;
    float inv = 1.f / (float)(cnt > 0 ? cnt : 1);
    float fx = (float)ax * FIXINV * inv;    // FIXINV mult is exact (pow2)
    float fy = (float)ay * FIXINV * inv;
    unsigned short lo = (unsigned short)f2bf(fx);
    unsigned short hi = (unsigned short)f2bf(fy);
    *(unsigned*)(agg + (size_t)n * 384 + r * 128 + lane * 2) = (unsigned)lo | ((unsigned)hi << 16);
}

// ---- classifier + masked CE loss + DETERMINISTIC fixed-order loss reduce ----
__global__ __launch_bounds__(256) void cls_loss_kernel(
    const short* __restrict__ lm, const short* __restrict__ g,
    const float* __restrict__ clsW, const float* __restrict__ clsb,
    const int* __restrict__ mask, const int* __restrict__ labels,
    float* __restrict__ logits, float* __restrict__ partials,
    unsigned* __restrict__ ticket, float* __restrict__ loss_out)
{
    __shared__ float W[2048];
    __shared__ float pl4[4], pc4[4];
    __shared__ unsigned lastflag;
    __shared__ float sl[128], sc[128];
    for (int i = threadIdx.x; i < 2048; i += 256) W[i] = clsW[i];
    __syncthreads();
    int n = blockIdx.x * 256 + threadIdx.x;
    float l[8];
    #pragma unroll
    for (int c = 0; c < 8; ++c) l[c] = clsb[c];
    const short* lmr = lm + (size_t)n * 128;
    const short* gr  = g  + (size_t)n * 128;
    #pragma unroll 2
    for (int h = 0; h < 128; h += 8) {
        uint4 raw = *(const uint4*)(lmr + h);
        float a[8];
        a[0] = bf2f((unsigned short)(raw.x & 0xffff)); a[1] = bf2f((unsigned short)(raw.x >> 16));
        a[2] = bf2f((unsigned short)(raw.y & 0xffff)); a[3] = bf2f((unsigned short)(raw.y >> 16));
        a[4] = bf2f((unsigned short)(raw.z & 0xffff)); a[5] = bf2f((unsigned short)(raw.z >> 16));
        a[6] = bf2f((unsigned short)(raw.w & 0xffff)); a[7] = bf2f((unsigned short)(raw.w >> 16));
        #pragma unroll
        for (int c = 0; c < 8; ++c) {
            const float* w = &W[c * 256 + h];
            #pragma unroll
            for (int j = 0; j < 8; ++j) l[c] = fmaf(a[j], w[j], l[c]);
        }
    }
    #pragma unroll 2
    for (int h = 0; h < 128; h += 8) {
        uint4 raw = *(const uint4*)(gr + h);
        float a[8];
        a[0] = bf2f((unsigned short)(raw.x & 0xffff)); a[1] = bf2f((unsigned short)(raw.x >> 16));
        a[2] = bf2f((unsigned short)(raw.y & 0xffff)); a[3] = bf2f((unsigned short)(raw.y >> 16));
        a[4] = bf2f((unsigned short)(raw.z & 0xffff)); a[5] = bf2f((unsigned short)(raw.z >> 16));
        a[6] = bf2f((unsigned short)(raw.w & 0xffff)); a[7] = bf2f((unsigned short)(raw.w >> 16));
        #pragma unroll
        for (int c = 0; c < 8; ++c) {
            const float* w = &W[c * 256 + 128 + h];
            #pragma unroll
            for (int j = 0; j < 8; ++j) l[c] = fmaf(a[j], w[j], l[c]);
        }
    }
    #pragma unroll
    for (int c = 0; c < 8; ++c) logits[(size_t)n * 8 + c] = l[c];

    float m = l[0];
    #pragma unroll
    for (int c = 1; c < 8; ++c) m = fmaxf(m, l[c]);
    float ss = 0.f;
    #pragma unroll
    for (int c = 0; c < 8; ++c) ss += expf(l[c] - m);
    float lse = m + logf(ss);
    int y = labels[n];
    float ly = l[0];
    #pragma unroll
    for (int c = 1; c < 8; ++c) ly = (y == c) ? l[c] : ly;
    float nll = lse - ly;
    bool valid = (mask[n] == 1);
    float lv = valid ? nll : 0.f;
    float cv = valid ? 1.f : 0.f;
    #pragma unroll
    for (int off = 32; off > 0; off >>= 1) {
        lv += __shfl_down(lv, off, 64);
        cv += __shfl_down(cv, off, 64);
    }
    if ((threadIdx.x & 63) == 0) { pl4[threadIdx.x >> 6] = lv; pc4[threadIdx.x >> 6] = cv; }
    __syncthreads();
    if (threadIdx.x == 0) {
        // fixed-order in-block combine -> deterministic partials
        float L = ((pl4[0] + pl4[1]) + pl4[2]) + pl4[3];
        float C = ((pc4[0] + pc4[1]) + pc4[2]) + pc4[3];
        partials[2 * blockIdx.x]     = L;
        partials[2 * blockIdx.x + 1] = C;
        __threadfence();
        unsigned tk = atomicAdd(ticket, 1u);
        lastflag = (tk == gridDim.x - 1) ? 1u : 0u;
    }
    __syncthreads();
    if (lastflag) {
        if (threadIdx.x < 128) {
            sl[threadIdx.x] = atomicAdd(&partials[2 * threadIdx.x], 0.f);     // coherent read
            sc[threadIdx.x] = atomicAdd(&partials[2 * threadIdx.x + 1], 0.f);
        }
        __syncthreads();
        if (threadIdx.x == 0) {
            float L = 0.f, C = 0.f;
            for (int j = 0; j < 128; ++j) { L += sl[j]; C += sc[j]; }   // fixed order
            loss_out[0] = L / fmaxf(C, 1.f);
        }
    }
}

// ---- launcher ----
extern "C" void kernel_launch(void* const* d_in, const int* in_sizes, int n_in,
                              void* d_out, int out_size, void* d_ws, size_t ws_size,
                              hipStream_t stream)
{
    const float* output = (const float*)d_in[0];
    const int* edge_index = (const int*)d_in[1];
    const int* edge_type  = (const int*)d_in[2];
    const int* attn       = (const int*)d_in[3];
    const int* labels     = (const int*)d_in[4];
    const float* lmW   = (const float*)d_in[5];
    const float* lmb   = (const float*)d_in[6];
    const float* lng   = (const float*)d_in[7];
    const float* lnb   = (const float*)d_in[8];
    const float* Wrel  = (const float*)d_in[9];
    const float* Wroot = (const float*)d_in[10];
    const float* convb = (const float*)d_in[11];
    const float* clsW  = (const float*)d_in[12];
    const float* clsb  = (const float*)d_in[13];

    char* ws = (char*)d_ws;
    short* lm_bf  = (short*)ws;                          ws += (size_t)Nn * Dd * 2;
    short* x1_bf  = (short*)ws;                          ws += (size_t)Nn * Dd * 2;
    short* x2_bf  = (short*)ws;                          ws += (size_t)Nn * Dd * 2;
    short* agg_bf = (short*)ws;                          ws += (size_t)Nn * 384 * 2;
    short* Wp_all = (short*)ws;                          ws += (size_t)262144 * 2;
    // zeroed region: [ticket pad | counts | fill] contiguous
    float* zbase  = (float*)ws;                          ws += 64;
    int* counts   = (int*)ws;                            ws += (size_t)NSEG * 4;
    int* fill     = (int*)ws;                            ws += (size_t)NSEG * 4;
    int* row_ptr  = (int*)ws;                            ws += (size_t)(NSEG + 4) * 4;
    int* excl     = (int*)ws;                            ws += (size_t)NSEG * 4;
    int* blksum   = (int*)ws;                            ws += 512 * 4;
    float* partials = (float*)ws;                        ws += 256 * 4;   // fully written
    int* edge_src = (int*)ws;

    unsigned* ticket = (unsigned*)(zbase + 2);           // inside zeroed pad

    short* Wp_lm = Wp_all;
    short* Wp_c0 = Wp_all + 131072;
    short* Wp_c1 = Wp_all + 131072 + 65536;

    const int* e_src = edge_index;
    const int* e_dst = edge_index + Ee;

    hipMemsetAsync(zbase, 0, 64 + 2 * (size_t)NSEG * 4, stream);

    // pack weights + edge histogram (fused)
    prep_kernel<<<dim3(1024 + Ee / 256), dim3(256), 0, stream>>>(
        lmW, Wrel, Wroot, Wp_all, e_dst, edge_type, counts);

    // LM head + ReLU + fused LN
    lm_gemm_ln_kernel<<<dim3(Nn / 64), dim3(256), 0, stream>>>(
        output, Wp_lm, lmb, lng, lnb, lm_bf);

    // CSR over (dst, relation)
    scan_blk_kernel<<<dim3(NSEG / 256), dim3(256), 0, stream>>>(counts, excl, blksum);
    scan_add_kernel<<<dim3(NSEG / 256), dim3(256), 0, stream>>>(excl, blksum, row_ptr);
    scatter_kernel<<<dim3(Ee / 256), dim3(256), 0, stream>>>(
        e_src, e_dst, edge_type, row_ptr, fill, edge_src);

    // RGCN layers (TLP-rich aggregate, deterministic int64 accumulation)
    aggregate_kernel<<<dim3(NSEG / 4), dim3(256), 0, stream>>>(lm_bf, row_ptr, edge_src, agg_bf);
    conv_gemm_kernel<<<dim3(Nn / 64), dim3(256), 0, stream>>>(
        agg_bf, lm_bf, Wp_c0, convb, x1_bf);
    aggregate_kernel<<<dim3(NSEG / 4), dim3(256), 0, stream>>>(x1_bf, row_ptr, edge_src, agg_bf);
    conv_gemm_kernel<<<dim3(Nn / 64), dim3(256), 0, stream>>>(
        agg_bf, x1_bf, Wp_c1, convb + Dd, x2_bf);

    // classifier + loss + deterministic fused finalize
    float* logits = (float*)d_out + 1;
    cls_loss_kernel<<<dim3(Nn / 256), dim3(256), 0, stream>>>(
        lm_bf, x2_bf, clsW, clsb, attn, labels, logits, partials, ticket, (float*)d_out);
}

// Round 12
// 451.053 us; speedup vs baseline: 1.1325x; 1.0040x over previous
//
#include <hip/hip_runtime.h>

#define Bb 32
#define Ll 1024
#define LMD 1024
#define Dd 128
#define Rr 3
#define NLAYER 2
#define Cc 8
#define Nn (Bb*Ll)          // 32768
#define Ee 524288
#define NSEG (Nn*Rr)        // 98304
#define LN_EPS 1e-5f
#define FIXSCALE 1073741824.0f      // 2^30
#define FIXINV   (1.0f / 1073741824.0f)

typedef __attribute__((ext_vector_type(8))) short bf16x8;
typedef __attribute__((ext_vector_type(4))) float f32x4;

__device__ inline short f2bf(float f) {
    unsigned u = __builtin_bit_cast(unsigned, f);
    u += 0x7fff + ((u >> 16) & 1);           // RNE
    return (short)(u >> 16);
}
__device__ inline float bf2f(unsigned short s) {
    unsigned u = ((unsigned)s) << 16;
    return __builtin_bit_cast(float, u);
}
// deterministic fixed-point quantizer (order-independent accumulation)
__device__ inline long long q30(float v) {
    return (long long)llrintf(v * FIXSCALE);
}

// ---- prep: weight pack (blocks 0..1023) + edge histogram (blocks 1024..3071)
__global__ __launch_bounds__(256) void prep_kernel(
    const float* __restrict__ lmW, const float* __restrict__ Wrel,
    const float* __restrict__ Wroot, short* __restrict__ Wp_all,
    const int* __restrict__ dst, const int* __restrict__ et,
    int* __restrict__ counts)
{
    int bid = blockIdx.x;
    if (bid < 1024) {
        int idx = bid * 256 + threadIdx.x;   // 0..262143
        float v;
        if (idx < 131072) {
            int kk = idx & 31, n = (idx >> 5) & 127, ks = idx >> 12;
            v = lmW[n * 1024 + ks * 32 + kk];
        } else {
            int j = idx - 131072;
            int layer = j >> 16;
            int kk = j & 31, n = (j >> 5) & 127, ks = (j >> 12) & 15;
            int k = ks * 32 + kk;
            v = (k < 384) ? Wrel[(size_t)layer * 49152 + (size_t)k * 128 + n]
                          : Wroot[(size_t)layer * 16384 + (size_t)(k - 384) * 128 + n];
        }
        Wp_all[idx] = f2bf(v);
    } else {
        int e = (bid - 1024) * 256 + threadIdx.x;   // 0..Ee-1
        atomicAdd(&counts[dst[e] * 3 + et[e]], 1);
    }
}

// ---- LM head GEMM (MFMA bf16) + bias + ReLU + fused LayerNorm (r10 verbatim) ----
__global__ __launch_bounds__(256) void lm_gemm_ln_kernel(
    const float* __restrict__ A,        // [M,1024] fp32
    const short* __restrict__ Wp,       // [32][128][32] bf16 frag-packed
    const float* __restrict__ bias,     // [128]
    const float* __restrict__ lng, const float* __restrict__ lnb,
    short* __restrict__ lm_bf16)
{
    const int wv   = threadIdx.x >> 6;
    const int lane = threadIdx.x & 63;
    const int m16  = lane & 15;
    const int quad = lane >> 4;
    const int row_frag = blockIdx.x * 64 + wv * 16 + m16;
    const float* arow = A + (size_t)row_frag * 1024 + quad * 8;

    f32x4 acc[8];
    #pragma unroll
    for (int i = 0; i < 8; ++i) acc[i] = (f32x4){0.f, 0.f, 0.f, 0.f};

    #pragma unroll 2
    for (int ks = 0; ks < 32; ++ks) {
        const short* wpb = Wp + ks * 4096 + m16 * 32 + quad * 8;
        bf16x8 bfr[8];
        #pragma unroll
        for (int nt = 0; nt < 8; ++nt)
            bfr[nt] = *(const bf16x8*)(wpb + nt * 512);
        const float4* ap = (const float4*)(arow + ks * 32);
        float4 a0 = ap[0], a1 = ap[1];
        union { bf16x8 v; short s[8]; } af;
        af.s[0] = f2bf(a0.x); af.s[1] = f2bf(a0.y);
        af.s[2] = f2bf(a0.z); af.s[3] = f2bf(a0.w);
        af.s[4] = f2bf(a1.x); af.s[5] = f2bf(a1.y);
        af.s[6] = f2bf(a1.z); af.s[7] = f2bf(a1.w);
        #pragma unroll
        for (int nt = 0; nt < 8; ++nt)
            acc[nt] = __builtin_amdgcn_mfma_f32_16x16x32_bf16(af.v, bfr[nt], acc[nt], 0, 0, 0);
    }

    float v[8][4];
    #pragma unroll
    for (int nt = 0; nt < 8; ++nt) {
        float bs = bias[nt * 16 + m16];
        #pragma unroll
        for (int r = 0; r < 4; ++r) v[nt][r] = fmaxf(acc[nt][r] + bs, 0.f);
    }
    float gv[8], bv[8];
    #pragma unroll
    for (int nt = 0; nt < 8; ++nt) { gv[nt] = lng[nt * 16 + m16]; bv[nt] = lnb[nt * 16 + m16]; }

    const int row0 = blockIdx.x * 64 + wv * 16 + quad * 4;
    #pragma unroll
    for (int r = 0; r < 4; ++r) {
        float s = 0.f;
        #pragma unroll
        for (int nt = 0; nt < 8; ++nt) s += v[nt][r];
        s += __shfl_xor(s, 1, 64); s += __shfl_xor(s, 2, 64);
        s += __shfl_xor(s, 4, 64); s += __shfl_xor(s, 8, 64);
        float mu = s * (1.f / 128.f);
        float q = 0.f;
        #pragma unroll
        for (int nt = 0; nt < 8; ++nt) { float d = v[nt][r] - mu; q += d * d; }
        q += __shfl_xor(q, 1, 64); q += __shfl_xor(q, 2, 64);
        q += __shfl_xor(q, 4, 64); q += __shfl_xor(q, 8, 64);
        float rs = rsqrtf(q * (1.f / 128.f) + LN_EPS);
        size_t rowoff = (size_t)(row0 + r) * 128;
        #pragma unroll
        for (int nt = 0; nt < 8; ++nt) {
            float o = (v[nt][r] - mu) * rs * gv[nt] + bv[nt];
            lm_bf16[rowoff + nt * 16 + m16] = f2bf(o);
        }
    }
}

// ---- conv GEMM (MFMA bf16): out = relu([agg|x] * Wc + bias), K=512 (r10 verbatim) ----
__global__ __launch_bounds__(256) void conv_gemm_kernel(
    const short* __restrict__ A1,       // [N,384] bf16 (agg)
    const short* __restrict__ A2,       // [N,128] bf16 (x)
    const short* __restrict__ Wp,       // [16][128][32] bf16 frag-packed
    const float* __restrict__ bias,
    short* __restrict__ out_bf16)       // [N,128]
{
    const int wv   = threadIdx.x >> 6;
    const int lane = threadIdx.x & 63;
    const int m16  = lane & 15;
    const int quad = lane >> 4;
    const int row_frag = blockIdx.x * 64 + wv * 16 + m16;
    const short* a1row = A1 + (size_t)row_frag * 384 + quad * 8;
    const short* a2row = A2 + (size_t)row_frag * 128 + quad * 8;

    f32x4 acc[8];
    #pragma unroll
    for (int i = 0; i < 8; ++i) acc[i] = (f32x4){0.f, 0.f, 0.f, 0.f};

    #pragma unroll 2
    for (int ks = 0; ks < 16; ++ks) {
        const short* wpb = Wp + ks * 4096 + m16 * 32 + quad * 8;
        bf16x8 bfr[8];
        #pragma unroll
        for (int nt = 0; nt < 8; ++nt)
            bfr[nt] = *(const bf16x8*)(wpb + nt * 512);
        const short* ar = (ks < 12) ? (a1row + ks * 32) : (a2row + (ks - 12) * 32);
        bf16x8 af = *(const bf16x8*)ar;
        #pragma unroll
        for (int nt = 0; nt < 8; ++nt)
            acc[nt] = __builtin_amdgcn_mfma_f32_16x16x32_bf16(af, bfr[nt], acc[nt], 0, 0, 0);
    }

    const int row0 = blockIdx.x * 64 + wv * 16 + quad * 4;
    #pragma unroll
    for (int nt = 0; nt < 8; ++nt) {
        float bs = bias[nt * 16 + m16];
        #pragma unroll
        for (int r = 0; r < 4; ++r) {
            float o = fmaxf(acc[nt][r] + bs, 0.f);
            out_bf16[(size_t)(row0 + r) * 128 + nt * 16 + m16] = f2bf(o);
        }
    }
}

// ---- CSR scan (hierarchical, r6-verified) ----
__global__ __launch_bounds__(256) void scan_blk_kernel(
    const int* __restrict__ counts, int* __restrict__ excl, int* __restrict__ blksum)
{
    __shared__ int wsum[4];
    int t = threadIdx.x, lane = t & 63, wv = t >> 6;
    int g = blockIdx.x * 256 + t;
    int v = counts[g];
    int x = v;
    #pragma unroll
    for (int off = 1; off < 64; off <<= 1) {
        int y = __shfl_up(x, off, 64);
        if (lane >= off) x += y;
    }
    if (lane == 63) wsum[wv] = x;
    __syncthreads();
    int woff = 0;
    for (int i = 0; i < wv; ++i) woff += wsum[i];
    excl[g] = woff + x - v;
    if (t == 255) blksum[blockIdx.x] = woff + x;
}

__global__ __launch_bounds__(256) void scan_add_kernel(
    const int* __restrict__ excl, const int* __restrict__ blksum,
    int* __restrict__ row_ptr)
{
    __shared__ int ws4[4];
    __shared__ int off_sh;
    const int t = threadIdx.x, bid = blockIdx.x;
    int s = 0;
    for (int j = t; j < bid; j += 256) s += blksum[j];
    #pragma unroll
    for (int o = 32; o > 0; o >>= 1) s += __shfl_xor(s, o, 64);
    if ((t & 63) == 0) ws4[t >> 6] = s;
    __syncthreads();
    if (t == 0) off_sh = ws4[0] + ws4[1] + ws4[2] + ws4[3];
    __syncthreads();
    int g = bid * 256 + t;
    row_ptr[g] = excl[g] + off_sh;
    if (g == 0) row_ptr[NSEG] = Ee;
}

__global__ __launch_bounds__(256) void scatter_kernel(
    const int* __restrict__ src, const int* __restrict__ dst, const int* __restrict__ et,
    const int* __restrict__ row_ptr, int* __restrict__ fill, int* __restrict__ edge_src)
{
    int e = blockIdx.x * 256 + threadIdx.x;
    int s = dst[e] * 3 + et[e];
    int pos = row_ptr[s] + atomicAdd(&fill[s], 1);
    edge_src[pos] = src[e];
}

// ---- per-(node,relation) mean aggregation, DETERMINISTIC int64 fixed-point ----
__global__ __launch_bounds__(256) void aggregate_kernel(
    const short* __restrict__ x, const int* __restrict__ row_ptr,
    const int* __restrict__ edge_src, short* __restrict__ agg)
{
    int seg  = blockIdx.x * 4 + (threadIdx.x >> 6);
    int lane = threadIdx.x & 63;
    int b = row_ptr[seg], e = row_ptr[seg + 1];
    int n = seg / 3, r = seg - n * 3;
    long long ax = 0, ay = 0;
    int i = b;
    for (; i + 4 <= e; i += 4) {
        int s0 = edge_src[i],     s1 = edge_src[i + 1];
        int s2 = edge_src[i + 2], s3 = edge_src[i + 3];
        unsigned u0 = *(const unsigned*)(x + (size_t)s0 * 128 + lane * 2);
        unsigned u1 = *(const unsigned*)(x + (size_t)s1 * 128 + lane * 2);
        unsigned u2 = *(const unsigned*)(x + (size_t)s2 * 128 + lane * 2);
        unsigned u3 = *(const unsigned*)(x + (size_t)s3 * 128 + lane * 2);
        ax += q30(bf2f((unsigned short)(u0 & 0xffff))) + q30(bf2f((unsigned short)(u1 & 0xffff)))
            + q30(bf2f((unsigned short)(u2 & 0xffff))) + q30(bf2f((unsigned short)(u3 & 0xffff)));
        ay += q30(bf2f((unsigned short)(u0 >> 16))) + q30(bf2f((unsigned short)(u1 >> 16)))
            + q30(bf2f((unsigned short)(u2 >> 16))) + q30(bf2f((unsigned short)(u3 >> 16)));
    }
    for (; i + 2 <= e; i += 2) {
        int s0 = edge_src[i], s1 = edge_src[i + 1];
        unsigned u0 = *(const unsigned*)(x + (size_t)s0 * 128 + lane * 2);
        unsigned u1 = *(const unsigned*)(x + (size_t)s1 * 128 + lane * 2);
        ax += q30(bf2f((unsigned short)(u0 & 0xffff))) + q30(bf2f((unsigned short)(u1 & 0xffff)));
        ay += q30(bf2f((unsigned short)(u0 >> 16)))    + q30(bf2f((unsigned short)(u1 >> 16)));
    }
    if (i < e) {
        int s0 = edge_src[i];
        unsigned u0 = *(const unsigned*)(x + (size_t)s0 * 128 + lane * 2);
        ax += q30(bf2f((unsigned short)(u0 & 0xffff)));
        ay += q30(bf2f((unsigned short)(u0 >> 16)));
    }
    int cnt = e - b;
    float inv = 1.f / (float)(cnt > 0 ? cnt : 1);
    float fx = (float)ax * FIXINV * inv;    // FIXINV mult is exact (pow2)
    float fy = (float)ay * FIXINV * inv;
    unsigned short lo = (unsigned short)f2bf(fx);
    unsigned short hi = (unsigned short)f2bf(fy);
    *(unsigned*)(agg + (size_t)n * 384 + r * 128 + lane * 2) = (unsigned)lo | ((unsigned)hi << 16);
}

// ---- classifier + masked CE loss + DETERMINISTIC fixed-order loss reduce ----
__global__ __launch_bounds__(256) void cls_loss_kernel(
    const short* __restrict__ lm, const short* __restrict__ g,
    const float* __restrict__ clsW, const float* __restrict__ clsb,
    const int* __restrict__ mask, const int* __restrict__ labels,
    float* __restrict__ logits, float* __restrict__ partials,
    unsigned* __restrict__ ticket, float* __restrict__ loss_out)
{
    __shared__ float W[2048];
    __shared__ float pl4[4], pc4[4];
    __shared__ unsigned lastflag;
    __shared__ float sl[128], sc[128];
    for (int i = threadIdx.x; i < 2048; i += 256) W[i] = clsW[i];
    __syncthreads();
    int n = blockIdx.x * 256 + threadIdx.x;
    float l[8];
    #pragma unroll
    for (int c = 0; c < 8; ++c) l[c] = clsb[c];
    const short* lmr = lm + (size_t)n * 128;
    const short* gr  = g  + (size_t)n * 128;
    #pragma unroll 2
    for (int h = 0; h < 128; h += 8) {
        uint4 raw = *(const uint4*)(lmr + h);
        float a[8];
        a[0] = bf2f((unsigned short)(raw.x & 0xffff)); a[1] = bf2f((unsigned short)(raw.x >> 16));
        a[2] = bf2f((unsigned short)(raw.y & 0xffff)); a[3] = bf2f((unsigned short)(raw.y >> 16));
        a[4] = bf2f((unsigned short)(raw.z & 0xffff)); a[5] = bf2f((unsigned short)(raw.z >> 16));
        a[6] = bf2f((unsigned short)(raw.w & 0xffff)); a[7] = bf2f((unsigned short)(raw.w >> 16));
        #pragma unroll
        for (int c = 0; c < 8; ++c) {
            const float* w = &W[c * 256 + h];
            #pragma unroll
            for (int j = 0; j < 8; ++j) l[c] = fmaf(a[j], w[j], l[c]);
        }
    }
    #pragma unroll 2
    for (int h = 0; h < 128; h += 8) {
        uint4 raw = *(const uint4*)(gr + h);
        float a[8];
        a[0] = bf2f((unsigned short)(raw.x & 0xffff)); a[1] = bf2f((unsigned short)(raw.x >> 16));
        a[2] = bf2f((unsigned short)(raw.y & 0xffff)); a[3] = bf2f((unsigned short)(raw.y >> 16));
        a[4] = bf2f((unsigned short)(raw.z & 0xffff)); a[5] = bf2f((unsigned short)(raw.z >> 16));
        a[6] = bf2f((unsigned short)(raw.w & 0xffff)); a[7] = bf2f((unsigned short)(raw.w >> 16));
        #pragma unroll
        for (int c = 0; c < 8; ++c) {
            const float* w = &W[c * 256 + 128 + h];
            #pragma unroll
            for (int j = 0; j < 8; ++j) l[c] = fmaf(a[j], w[j], l[c]);
        }
    }
    #pragma unroll
    for (int c = 0; c < 8; ++c) logits[(size_t)n * 8 + c] = l[c];

    float m = l[0];
    #pragma unroll
    for (int c = 1; c < 8; ++c) m = fmaxf(m, l[c]);
    float ss = 0.f;
    #pragma unroll
    for (int c = 0; c < 8; ++c) ss += expf(l[c] - m);
    float lse = m + logf(ss);
    int y = labels[n];
    float ly = l[0];
    #pragma unroll
    for (int c = 1; c < 8; ++c) ly = (y == c) ? l[c] : ly;
    float nll = lse - ly;
    bool valid = (mask[n] == 1);
    float lv = valid ? nll : 0.f;
    float cv = valid ? 1.f : 0.f;
    #pragma unroll
    for (int off = 32; off > 0; off >>= 1) {
        lv += __shfl_down(lv, off, 64);
        cv += __shfl_down(cv, off, 64);
    }
    if ((threadIdx.x & 63) == 0) { pl4[threadIdx.x >> 6] = lv; pc4[threadIdx.x >> 6] = cv; }
    __syncthreads();
    if (threadIdx.x == 0) {
        float L = ((pl4[0] + pl4[1]) + pl4[2]) + pl4[3];
        float C = ((pc4[0] + pc4[1]) + pc4[2]) + pc4[3];
        partials[2 * blockIdx.x]     = L;
        partials[2 * blockIdx.x + 1] = C;
        __threadfence();
        unsigned tk = atomicAdd(ticket, 1u);
        lastflag = (tk == gridDim.x - 1) ? 1u : 0u;
    }
    __syncthreads();
    if (lastflag) {
        if (threadIdx.x < 128) {
            sl[threadIdx.x] = atomicAdd(&partials[2 * threadIdx.x], 0.f);
            sc[threadIdx.x] = atomicAdd(&partials[2 * threadIdx.x + 1], 0.f);
        }
        __syncthreads();
        if (threadIdx.x == 0) {
            float L = 0.f, C = 0.f;
            for (int j = 0; j < 128; ++j) { L += sl[j]; C += sc[j]; }
            loss_out[0] = L / fmaxf(C, 1.f);
        }
    }
}

// ---- launcher ----
extern "C" void kernel_launch(void* const* d_in, const int* in_sizes, int n_in,
                              void* d_out, int out_size, void* d_ws, size_t ws_size,
                              hipStream_t stream)
{
    const float* output = (const float*)d_in[0];
    const int* edge_index = (const int*)d_in[1];
    const int* edge_type  = (const int*)d_in[2];
    const int* attn       = (const int*)d_in[3];
    const int* labels     = (const int*)d_in[4];
    const float* lmW   = (const float*)d_in[5];
    const float* lmb   = (const float*)d_in[6];
    const float* lng   = (const float*)d_in[7];
    const float* lnb   = (const float*)d_in[8];
    const float* Wrel  = (const float*)d_in[9];
    const float* Wroot = (const float*)d_in[10];
    const float* convb = (const float*)d_in[11];
    const float* clsW  = (const float*)d_in[12];
    const float* clsb  = (const float*)d_in[13];

    char* ws = (char*)d_ws;
    short* lm_bf  = (short*)ws;                          ws += (size_t)Nn * Dd * 2;
    short* x1_bf  = (short*)ws;                          ws += (size_t)Nn * Dd * 2;
    short* x2_bf  = (short*)ws;                          ws += (size_t)Nn * Dd * 2;
    short* agg_bf = (short*)ws;                          ws += (size_t)Nn * 384 * 2;
    short* Wp_all = (short*)ws;                          ws += (size_t)262144 * 2;
    // zeroed region: [ticket pad | counts | fill] contiguous
    float* zbase  = (float*)ws;                          ws += 64;
    int* counts   = (int*)ws;                            ws += (size_t)NSEG * 4;
    int* fill     = (int*)ws;                            ws += (size_t)NSEG * 4;
    int* row_ptr  = (int*)ws;                            ws += (size_t)(NSEG + 4) * 4;
    int* excl     = (int*)ws;                            ws += (size_t)NSEG * 4;
    int* blksum   = (int*)ws;                            ws += 512 * 4;
    float* partials = (float*)ws;                        ws += 256 * 4;   // fully written
    int* edge_src = (int*)ws;

    unsigned* ticket = (unsigned*)(zbase + 2);           // inside zeroed pad

    short* Wp_lm = Wp_all;
    short* Wp_c0 = Wp_all + 131072;
    short* Wp_c1 = Wp_all + 131072 + 65536;

    const int* e_src = edge_index;
    const int* e_dst = edge_index + Ee;

    hipMemsetAsync(zbase, 0, 64 + 2 * (size_t)NSEG * 4, stream);

    // pack weights + edge histogram (fused)
    prep_kernel<<<dim3(1024 + Ee / 256), dim3(256), 0, stream>>>(
        lmW, Wrel, Wroot, Wp_all, e_dst, edge_type, counts);

    // LM head + ReLU + fused LN
    lm_gemm_ln_kernel<<<dim3(Nn / 64), dim3(256), 0, stream>>>(
        output, Wp_lm, lmb, lng, lnb, lm_bf);

    // CSR over (dst, relation)
    scan_blk_kernel<<<dim3(NSEG / 256), dim3(256), 0, stream>>>(counts, excl, blksum);
    scan_add_kernel<<<dim3(NSEG / 256), dim3(256), 0, stream>>>(excl, blksum, row_ptr);
    scatter_kernel<<<dim3(Ee / 256), dim3(256), 0, stream>>>(
        e_src, e_dst, edge_type, row_ptr, fill, edge_src);

    // RGCN layers (TLP-rich aggregate, deterministic int64 accumulation)
    aggregate_kernel<<<dim3(NSEG / 4), dim3(256), 0, stream>>>(lm_bf, row_ptr, edge_src, agg_bf);
    conv_gemm_kernel<<<dim3(Nn / 64), dim3(256), 0, stream>>>(
        agg_bf, lm_bf, Wp_c0, convb, x1_bf);
    aggregate_kernel<<<dim3(NSEG / 4), dim3(256), 0, stream>>>(x1_bf, row_ptr, edge_src, agg_bf);
    conv_gemm_kernel<<<dim3(Nn / 64), dim3(256), 0, stream>>>(
        agg_bf, x1_bf, Wp_c1, convb + Dd, x2_bf);

    // classifier + loss + deterministic fused finalize
    float* logits = (float*)d_out + 1;
    cls_loss_kernel<<<dim3(Nn / 256), dim3(256), 0, stream>>>(
        lm_bf, x2_bf, clsW, clsb, attn, labels, logits, partials, ticket, (float*)d_out);
}